// Round 1
// baseline (700.463 us; speedup 1.0000x reference)
//
#include <hip/hip_runtime.h>
#include <math.h>

// Problem constants
constexpr int kB = 128;
constexpr int kT = 256;
constexpr int kC = 384;
constexpr int kH = 64;

// ---------------------------------------------------------------------------
// Kernel 1: fused QKV projection.  One block per row r of x [B*T, C].
// Threads 0..191: m = tid>>6 selects {Wq,Wk,Wv} (wave-uniform), h = tid&63.
// x row staged in LDS (broadcast reads), W reads coalesced per wave.
// ---------------------------------------------------------------------------
__global__ __launch_bounds__(256) void qkv_kernel(
    const float* __restrict__ x, const float* __restrict__ Wq,
    const float* __restrict__ Wk, const float* __restrict__ Wv,
    float* __restrict__ q, float* __restrict__ k, float* __restrict__ v)
{
    __shared__ float xs[kC];
    const int r   = blockIdx.x;          // [0, B*T)
    const int tid = threadIdx.x;
    const float* xrow = x + (size_t)r * kC;
    xs[tid] = xrow[tid];
    if (tid < kC - 256) xs[256 + tid] = xrow[256 + tid];
    __syncthreads();

    if (tid < 192) {
        const int m = tid >> 6;          // wave-uniform
        const int h = tid & 63;
        const float* W = (m == 0) ? Wq : (m == 1) ? Wk : Wv;
        float acc = 0.f;
#pragma unroll 8
        for (int c = 0; c < kC; ++c)
            acc = fmaf(xs[c], W[c * kH + h], acc);
        float* dst = (m == 0) ? q : (m == 1) ? k : v;
        dst[(size_t)r * kH + h] = acc;
    }
}

// ---------------------------------------------------------------------------
// Kernel 2: causal attention, one block per (b, t).
// wei[t,s] = (k_t . q_s) * C^-0.5  for s<=t; softmax over s; out = wei @ v.
// Thread s computes score s; block softmax; waves accumulate out over s-chunks.
// ---------------------------------------------------------------------------
__global__ __launch_bounds__(256) void attn_kernel(
    const float* __restrict__ q, const float* __restrict__ k,
    const float* __restrict__ v, float* __restrict__ out)
{
    const int t    = blockIdx.x;
    const int b    = blockIdx.y;
    const int tid  = threadIdx.x;
    const int lane = tid & 63;
    const int wave = tid >> 6;

    __shared__ float ks[kH];
    __shared__ float p[kT];
    __shared__ float red[4];
    __shared__ float pg[4][kH];

    const float* kt = k + ((size_t)b * kT + t) * kH;
    if (tid < kH) ks[tid] = kt[tid];
    __syncthreads();

    const float scale = 0.051031036307982884f;  // 384^-0.5 (C, per reference)

    float score = -INFINITY;
    if (tid <= t) {
        const float* qrow = q + ((size_t)b * kT + tid) * kH;
        float acc = 0.f;
#pragma unroll
        for (int h = 0; h < kH; h += 4) {
            float4 qv = *(const float4*)(qrow + h);
            acc = fmaf(ks[h],     qv.x, acc);
            acc = fmaf(ks[h + 1], qv.y, acc);
            acc = fmaf(ks[h + 2], qv.z, acc);
            acc = fmaf(ks[h + 3], qv.w, acc);
        }
        score = acc * scale;
    }

    // block max
    float m = score;
#pragma unroll
    for (int off = 32; off > 0; off >>= 1)
        m = fmaxf(m, __shfl_down(m, off, 64));
    if (lane == 0) red[wave] = m;
    __syncthreads();
    m = fmaxf(fmaxf(red[0], red[1]), fmaxf(red[2], red[3]));

    // exp + block sum
    float pv = (tid <= t) ? __expf(score - m) : 0.f;
    p[tid] = pv;
    float s = pv;
#pragma unroll
    for (int off = 32; off > 0; off >>= 1)
        s += __shfl_down(s, off, 64);
    __syncthreads();                 // red[] max-reads done; p[] now visible
    if (lane == 0) red[wave] = s;
    __syncthreads();
    s = red[0] + red[1] + red[2] + red[3];
    const float inv = 1.f / s;

    // out accumulation: wave g handles s in [g*64, g*64+64)
    float acc = 0.f;
    const int s0 = wave * 64;
    const int s1 = min(s0 + 64, t + 1);
    const float* vb = v + (size_t)b * kT * kH;
    for (int sI = s0; sI < s1; ++sI)
        acc = fmaf(p[sI], vb[(size_t)sI * kH + lane], acc);
    pg[wave][lane] = acc;
    __syncthreads();

    if (tid < kH)
        out[((size_t)b * kT + t) * kH + tid] =
            (pg[0][tid] + pg[1][tid] + pg[2][tid] + pg[3][tid]) * inv;
}

// ---------------------------------------------------------------------------
extern "C" void kernel_launch(void* const* d_in, const int* in_sizes, int n_in,
                              void* d_out, int out_size, void* d_ws, size_t ws_size,
                              hipStream_t stream) {
    const float* x  = (const float*)d_in[0];
    const float* Wq = (const float*)d_in[1];
    const float* Wk = (const float*)d_in[2];
    const float* Wv = (const float*)d_in[3];
    float* out = (float*)d_out;

    const size_t nqkv = (size_t)kB * kT * kH;   // 2,097,152 floats = 8 MB each
    float* q = (float*)d_ws;
    float* k = q + nqkv;
    float* v = k + nqkv;

    qkv_kernel<<<kB * kT, 256, 0, stream>>>(x, Wq, Wk, Wv, q, k, v);
    attn_kernel<<<dim3(kT, kB), 256, 0, stream>>>(q, k, v, out);
}

// Round 2
// 189.512 us; speedup vs baseline: 3.6961x; 3.6961x over previous
//
#include <hip/hip_runtime.h>
#include <math.h>

constexpr int kB = 128;
constexpr int kT = 256;
constexpr int kC = 384;
constexpr int kH = 64;

// ---------------------------------------------------------------------------
// Kernel 1: QKV projection as one GEMM: [32768 x 384] @ [384 x 192].
// Block tile: M=64, N=192 (q|k|v), K-step=64. 256 threads (tx=tid&15,
// ty=tid>>4), each owns a 4(M) x 12(N) register tile -> 48 indep accumulators.
// LDS: xs[kk][m] (transposed x tile, 16 KB) + ws[kk][n] (48 KB) = 64 KB.
// ---------------------------------------------------------------------------
__global__ __launch_bounds__(256) void qkv_kernel(
    const float* __restrict__ x, const float* __restrict__ Wq,
    const float* __restrict__ Wk, const float* __restrict__ Wv,
    float* __restrict__ q, float* __restrict__ k, float* __restrict__ v)
{
    __shared__ float xs[64][64];    // [kk][m]
    __shared__ float ws[64][192];   // [kk][n]  (writes/reads even across banks)

    const int tid = threadIdx.x;
    const int tx = tid & 15;        // N-group
    const int ty = tid >> 4;        // M-group
    const int m0 = blockIdx.x * 64;

    const int mrow = tid & 63;          // staging: one x row per lane
    const int kb   = (tid >> 6) * 16;   // staging: 16-col chunk per wave

    float acc[4][12];
#pragma unroll
    for (int i = 0; i < 4; ++i)
#pragma unroll
        for (int j = 0; j < 12; ++j) acc[i][j] = 0.f;

    for (int k0 = 0; k0 < kC; k0 += 64) {
        __syncthreads();   // previous iteration's LDS reads complete

        // stage x tile transposed: xs[kk][m]
        {
            const float* xr = x + (size_t)(m0 + mrow) * kC + k0 + kb;
            float4 a0 = ((const float4*)xr)[0];
            float4 a1 = ((const float4*)xr)[1];
            float4 a2 = ((const float4*)xr)[2];
            float4 a3 = ((const float4*)xr)[3];
            xs[kb +  0][mrow] = a0.x; xs[kb +  1][mrow] = a0.y;
            xs[kb +  2][mrow] = a0.z; xs[kb +  3][mrow] = a0.w;
            xs[kb +  4][mrow] = a1.x; xs[kb +  5][mrow] = a1.y;
            xs[kb +  6][mrow] = a1.z; xs[kb +  7][mrow] = a1.w;
            xs[kb +  8][mrow] = a2.x; xs[kb +  9][mrow] = a2.y;
            xs[kb + 10][mrow] = a2.z; xs[kb + 11][mrow] = a2.w;
            xs[kb + 12][mrow] = a3.x; xs[kb + 13][mrow] = a3.y;
            xs[kb + 14][mrow] = a3.z; xs[kb + 15][mrow] = a3.w;
        }
        // stage W tiles: 64x64 each of Wq/Wk/Wv -> ws[.][0/64/128 + .]
#pragma unroll
        for (int w = 0; w < 3; ++w) {
            const float* W = (w == 0) ? Wq : (w == 1) ? Wk : Wv;
#pragma unroll
            for (int i = 0; i < 4; ++i) {
                int f = tid + i * 256;      // float4 index within 64x64 tile
                int r = f >> 4;
                int c = (f & 15) * 4;
                float4 val = *(const float4*)(W + (size_t)(k0 + r) * kH + c);
                *(float4*)&ws[r][w * 64 + c] = val;
            }
        }
        __syncthreads();

#pragma unroll 4
        for (int kk = 0; kk < 64; ++kk) {
            float4 xa = *(const float4*)&xs[kk][ty * 4];
            float4 w0 = *(const float4*)&ws[kk][tx * 12];
            float4 w1 = *(const float4*)&ws[kk][tx * 12 + 4];
            float4 w2 = *(const float4*)&ws[kk][tx * 12 + 8];
            const float xr[4] = {xa.x, xa.y, xa.z, xa.w};
            const float wv[12] = {w0.x, w0.y, w0.z, w0.w,
                                  w1.x, w1.y, w1.z, w1.w,
                                  w2.x, w2.y, w2.z, w2.w};
#pragma unroll
            for (int i = 0; i < 4; ++i)
#pragma unroll
                for (int j = 0; j < 12; ++j)
                    acc[i][j] = fmaf(xr[i], wv[j], acc[i][j]);
        }
    }

    // epilogue: rows m0 + 4*ty + i, cols tx*12 + 4*jj (never straddles h=64)
#pragma unroll
    for (int i = 0; i < 4; ++i) {
        const size_t m = (size_t)(m0 + ty * 4 + i);
#pragma unroll
        for (int jj = 0; jj < 3; ++jj) {
            int col = tx * 12 + jj * 4;
            int w = col >> 6;
            int h = col & 63;
            float* dst = (w == 0) ? q : (w == 1) ? k : v;
            float4 o = make_float4(acc[i][jj * 4], acc[i][jj * 4 + 1],
                                   acc[i][jj * 4 + 2], acc[i][jj * 4 + 3]);
            *(float4*)(dst + m * kH + h) = o;
        }
    }
}

// ---------------------------------------------------------------------------
// Kernel 2: flash-style causal attention. Block = (b, 64-row t-tile).
// score(t,s) = (k_t . q_s) * 384^-0.5  (k plays the query role per reference).
// Thread (tx=tid&15, ty=tid>>4) owns rows 4ty+i; S-phase cols 4tx+j (s),
// PV-phase cols 4tx+j (h). Online softmax; P through LDS (stride 68).
// Qs buffer is reused for Ps after S-phase (barrier-protected).
// ---------------------------------------------------------------------------
__global__ __launch_bounds__(256) void attn_kernel(
    const float* __restrict__ q, const float* __restrict__ k,
    const float* __restrict__ v, float* __restrict__ out)
{
    __shared__ float Ks[64][64];       // [h][t], pre-scaled
    __shared__ float QP[64 * 68];      // Qs: [h][s] stride 64; Ps: [t][s] stride 68
    __shared__ float Vs[64][64];       // [s][h]

    const int b  = blockIdx.y;
    const int t0 = (3 - blockIdx.x) * 64;   // heavy tiles dispatch first
    const int tid = threadIdx.x;
    const int tx = tid & 15;
    const int ty = tid >> 4;

    const int r  = tid & 63;           // staging row per lane
    const int cb = (tid >> 6) * 16;    // staging col chunk per wave

    const float scale = 0.051031036307982884f;   // 384^-0.5

    // stage K tile transposed + scaled: Ks[h][t]
    {
        const float* kr = k + ((size_t)(b * kT + t0 + r)) * kH + cb;
        float4 a0 = ((const float4*)kr)[0];
        float4 a1 = ((const float4*)kr)[1];
        float4 a2 = ((const float4*)kr)[2];
        float4 a3 = ((const float4*)kr)[3];
        Ks[cb +  0][r] = a0.x * scale; Ks[cb +  1][r] = a0.y * scale;
        Ks[cb +  2][r] = a0.z * scale; Ks[cb +  3][r] = a0.w * scale;
        Ks[cb +  4][r] = a1.x * scale; Ks[cb +  5][r] = a1.y * scale;
        Ks[cb +  6][r] = a1.z * scale; Ks[cb +  7][r] = a1.w * scale;
        Ks[cb +  8][r] = a2.x * scale; Ks[cb +  9][r] = a2.y * scale;
        Ks[cb + 10][r] = a2.z * scale; Ks[cb + 11][r] = a2.w * scale;
        Ks[cb + 12][r] = a3.x * scale; Ks[cb + 13][r] = a3.y * scale;
        Ks[cb + 14][r] = a3.z * scale; Ks[cb + 15][r] = a3.w * scale;
    }

    float mrow[4], lrow[4], O[4][4];
#pragma unroll
    for (int i = 0; i < 4; ++i) {
        mrow[i] = -INFINITY; lrow[i] = 0.f;
#pragma unroll
        for (int j = 0; j < 4; ++j) O[i][j] = 0.f;
    }

    for (int s0 = 0; s0 <= t0; s0 += 64) {
        __syncthreads();   // prev PV reads done (iter0: K staging fence via next barrier)

        // stage Q tile transposed: QP[h*64+s]
        {
            const float* qr = q + ((size_t)(b * kT + s0 + r)) * kH + cb;
            float4 a0 = ((const float4*)qr)[0];
            float4 a1 = ((const float4*)qr)[1];
            float4 a2 = ((const float4*)qr)[2];
            float4 a3 = ((const float4*)qr)[3];
            QP[(cb +  0) * 64 + r] = a0.x; QP[(cb +  1) * 64 + r] = a0.y;
            QP[(cb +  2) * 64 + r] = a0.z; QP[(cb +  3) * 64 + r] = a0.w;
            QP[(cb +  4) * 64 + r] = a1.x; QP[(cb +  5) * 64 + r] = a1.y;
            QP[(cb +  6) * 64 + r] = a1.z; QP[(cb +  7) * 64 + r] = a1.w;
            QP[(cb +  8) * 64 + r] = a2.x; QP[(cb +  9) * 64 + r] = a2.y;
            QP[(cb + 10) * 64 + r] = a2.z; QP[(cb + 11) * 64 + r] = a2.w;
            QP[(cb + 12) * 64 + r] = a3.x; QP[(cb + 13) * 64 + r] = a3.y;
            QP[(cb + 14) * 64 + r] = a3.z; QP[(cb + 15) * 64 + r] = a3.w;
        }
        // stage V tile natural: Vs[s][h]
        {
            int sv = tid >> 2;
            int hb = (tid & 3) * 16;
            const float* vr = v + ((size_t)(b * kT + s0 + sv)) * kH + hb;
            float4 a0 = ((const float4*)vr)[0];
            float4 a1 = ((const float4*)vr)[1];
            float4 a2 = ((const float4*)vr)[2];
            float4 a3 = ((const float4*)vr)[3];
            *(float4*)&Vs[sv][hb +  0] = a0;
            *(float4*)&Vs[sv][hb +  4] = a1;
            *(float4*)&Vs[sv][hb +  8] = a2;
            *(float4*)&Vs[sv][hb + 12] = a3;
        }
        __syncthreads();

        // S = K-tile @ Q-tile^T : thread tile 4(t) x 4(s)
        float S[4][4];
#pragma unroll
        for (int i = 0; i < 4; ++i)
#pragma unroll
            for (int j = 0; j < 4; ++j) S[i][j] = 0.f;

#pragma unroll 8
        for (int h = 0; h < 64; ++h) {
            float4 ka = *(const float4*)&Ks[h][ty * 4];
            float4 qa = *(const float4*)&QP[h * 64 + tx * 4];
            const float kr4[4] = {ka.x, ka.y, ka.z, ka.w};
            const float qr4[4] = {qa.x, qa.y, qa.z, qa.w};
#pragma unroll
            for (int i = 0; i < 4; ++i)
#pragma unroll
                for (int j = 0; j < 4; ++j)
                    S[i][j] = fmaf(kr4[i], qr4[j], S[i][j]);
        }

        // causal mask on diagonal tile
        if (s0 == t0) {
#pragma unroll
            for (int i = 0; i < 4; ++i)
#pragma unroll
                for (int j = 0; j < 4; ++j)
                    if (tx * 4 + j > ty * 4 + i) S[i][j] = -INFINITY;
        }

        // online softmax row stats (rows live entirely within one wave)
        float P[4][4];
        float alpha[4];
#pragma unroll
        for (int i = 0; i < 4; ++i) {
            float rm = fmaxf(fmaxf(S[i][0], S[i][1]), fmaxf(S[i][2], S[i][3]));
            rm = fmaxf(rm, __shfl_xor(rm, 1, 64));
            rm = fmaxf(rm, __shfl_xor(rm, 2, 64));
            rm = fmaxf(rm, __shfl_xor(rm, 4, 64));
            rm = fmaxf(rm, __shfl_xor(rm, 8, 64));
            float mnew = fmaxf(mrow[i], rm);
            alpha[i] = __expf(mrow[i] - mnew);   // first tile: exp(-inf)=0
            mrow[i] = mnew;
            float rs = 0.f;
#pragma unroll
            for (int j = 0; j < 4; ++j) {
                P[i][j] = __expf(S[i][j] - mnew); // masked: exp(-inf)=0
                rs += P[i][j];
            }
            rs += __shfl_xor(rs, 1, 64);
            rs += __shfl_xor(rs, 2, 64);
            rs += __shfl_xor(rs, 4, 64);
            rs += __shfl_xor(rs, 8, 64);
            lrow[i] = lrow[i] * alpha[i] + rs;
#pragma unroll
            for (int j = 0; j < 4; ++j) O[i][j] *= alpha[i];
        }

        __syncthreads();   // all Qs reads done before Ps overwrites the buffer

        // write P: Ps[t][s], stride 68 (conflict-free reads across ty)
#pragma unroll
        for (int i = 0; i < 4; ++i)
            *(float4*)&QP[(ty * 4 + i) * 68 + tx * 4] =
                make_float4(P[i][0], P[i][1], P[i][2], P[i][3]);

        __syncthreads();

        // O += P @ V : thread tile 4(t) x 4(h)
#pragma unroll 4
        for (int s = 0; s < 64; s += 4) {
            float4 pr[4], vv[4];
#pragma unroll
            for (int i = 0; i < 4; ++i)
                pr[i] = *(const float4*)&QP[(ty * 4 + i) * 68 + s];
#pragma unroll
            for (int u = 0; u < 4; ++u)
                vv[u] = *(const float4*)&Vs[s + u][tx * 4];
#pragma unroll
            for (int i = 0; i < 4; ++i) {
                const float* pp = (const float*)&pr[i];
#pragma unroll
                for (int u = 0; u < 4; ++u) {
                    const float* vp = (const float*)&vv[u];
                    O[i][0] = fmaf(pp[u], vp[0], O[i][0]);
                    O[i][1] = fmaf(pp[u], vp[1], O[i][1]);
                    O[i][2] = fmaf(pp[u], vp[2], O[i][2]);
                    O[i][3] = fmaf(pp[u], vp[3], O[i][3]);
                }
            }
        }
    }

    // epilogue
#pragma unroll
    for (int i = 0; i < 4; ++i) {
        float inv = 1.f / lrow[i];
        float4 o = make_float4(O[i][0] * inv, O[i][1] * inv,
                               O[i][2] * inv, O[i][3] * inv);
        *(float4*)(out + ((size_t)(b * kT + t0 + ty * 4 + i)) * kH + tx * 4) = o;
    }
}

// ---------------------------------------------------------------------------
extern "C" void kernel_launch(void* const* d_in, const int* in_sizes, int n_in,
                              void* d_out, int out_size, void* d_ws, size_t ws_size,
                              hipStream_t stream) {
    const float* x  = (const float*)d_in[0];
    const float* Wq = (const float*)d_in[1];
    const float* Wk = (const float*)d_in[2];
    const float* Wv = (const float*)d_in[3];
    float* out = (float*)d_out;

    const size_t nqkv = (size_t)kB * kT * kH;   // 8 MB each
    float* q = (float*)d_ws;
    float* k = q + nqkv;
    float* v = k + nqkv;

    qkv_kernel<<<kB * kT / 64, 256, 0, stream>>>(x, Wq, Wk, Wv, q, k, v);
    attn_kernel<<<dim3(kT / 64, kB), 256, 0, stream>>>(q, k, v, out);
}

// Round 3
// 146.864 us; speedup vs baseline: 4.7695x; 1.2904x over previous
//
#include <hip/hip_runtime.h>
#include <hip/hip_bf16.h>
#include <math.h>

constexpr int kB = 128;
constexpr int kT = 256;
constexpr int kC = 384;
constexpr int kH = 64;

using bf16x8 = __attribute__((ext_vector_type(8))) short;  // 8 bf16 = 4 VGPRs
using f32x4  = __attribute__((ext_vector_type(4))) float;

union BF8 { bf16x8 v; __hip_bfloat162 h[4]; };

__device__ inline bf16x8 cvt8(float4 a, float4 b) {
    BF8 u;
    u.h[0] = __float22bfloat162_rn(float2{a.x, a.y});
    u.h[1] = __float22bfloat162_rn(float2{a.z, a.w});
    u.h[2] = __float22bfloat162_rn(float2{b.x, b.y});
    u.h[3] = __float22bfloat162_rn(float2{b.z, b.w});
    return u.v;
}

// ---------------------------------------------------------------------------
// Kernel 0: Wt[n][k] bf16, n in [0,192) = (w*64+h), k in [0,384).
// Wt[n][k] = W_w[k][h]; Wk rows pre-scaled by 384^-0.5 (k only feeds scores).
// ---------------------------------------------------------------------------
__global__ void prep_kernel(const float* __restrict__ Wq,
                            const float* __restrict__ Wk,
                            const float* __restrict__ Wv,
                            __hip_bfloat16* __restrict__ Wt) {
    int idx = blockIdx.x * 256 + threadIdx.x;     // [0, 192*384)
    int n = idx / kC, c = idx % kC;
    int w = n >> 6, h = n & 63;
    const float* W = (w == 0) ? Wq : (w == 1) ? Wk : Wv;
    float val = W[c * kH + h];
    if (w == 1) val *= 0.051031036307982884f;     // 384^-0.5
    Wt[idx] = __float2bfloat16(val);
}

// ---------------------------------------------------------------------------
// Kernel 1: QKV GEMM via MFMA 16x16x32 bf16. Block = 4 waves, M=64.
// Wave w: rows m0+16w..+15, all 192 cols (12 n-tiles). No LDS, no barriers.
// A-frag: x fp32 direct load + cvt (A[m=lane&15][k=quad*8+j]).
// B-frag: Wt contiguous 16 B (B[k=quad*8+j][n=lane&15]).
// Outputs bf16: q,k natural [m][64]; v transposed vT[b][h][s].
// ---------------------------------------------------------------------------
__global__ __launch_bounds__(256) void qkv_kernel(
    const float* __restrict__ x, const __hip_bfloat16* __restrict__ Wt,
    __hip_bfloat16* __restrict__ q, __hip_bfloat16* __restrict__ k,
    __hip_bfloat16* __restrict__ vT)
{
    const int tid  = threadIdx.x;
    const int wave = tid >> 6, lane = tid & 63;
    const int m16  = lane & 15, quad = lane >> 4;
    const int rowA = blockIdx.x * 64 + wave * 16 + m16;

    const float* xa = x + (size_t)rowA * kC + quad * 8;
    const short* wt = (const short*)Wt;

    f32x4 acc[12];
#pragma unroll
    for (int j = 0; j < 12; ++j) acc[j] = f32x4{0.f, 0.f, 0.f, 0.f};

    for (int k0 = 0; k0 < kC; k0 += 32) {
        float4 a0 = *(const float4*)(xa + k0);
        float4 a1 = *(const float4*)(xa + k0 + 4);
        bf16x8 af = cvt8(a0, a1);
#pragma unroll
        for (int j = 0; j < 12; ++j) {
            bf16x8 bf = *(const bf16x8*)(wt + (size_t)(j * 16 + m16) * kC + k0 + quad * 8);
            acc[j] = __builtin_amdgcn_mfma_f32_16x16x32_bf16(af, bf, acc[j], 0, 0, 0);
        }
    }

    // epilogue: C-layout col = m16 (within n-tile), row = quad*4 + r
    const int rbase = blockIdx.x * 64 + wave * 16 + quad * 4;
#pragma unroll
    for (int j = 0; j < 12; ++j) {
        const int w = j >> 2;
        const int h = (j & 3) * 16 + m16;
#pragma unroll
        for (int r = 0; r < 4; ++r) {
            const int m = rbase + r;
            __hip_bfloat16 val = __float2bfloat16(acc[j][r]);
            if (w == 0)      q[(size_t)m * kH + h] = val;
            else if (w == 1) k[(size_t)m * kH + h] = val;
            else             vT[((size_t)(m >> 8) * kH + h) * kT + (m & 255)] = val;
        }
    }
}

// ---------------------------------------------------------------------------
// Kernel 2: flash attention, all-MFMA. Block = 4 waves, wave-private bands.
// Wave: t-band [tb, tb+16). S = K·Q^T: A=k rows (contiguous), B=q rows
// (contiguous, n=s). Online softmax on C-layout (quad-wide shuffles).
// P: C-layout -> LDS (stride 33, 2-way max) -> A-layout + cvt bf16.
// PV: B = vT rows (contiguous, n=h). No __syncthreads (per-wave LDS,
// in-order DS pipe within a wave).
// ---------------------------------------------------------------------------
__global__ __launch_bounds__(256) void attn_kernel(
    const __hip_bfloat16* __restrict__ qg, const __hip_bfloat16* __restrict__ kg,
    const __hip_bfloat16* __restrict__ vTg, float* __restrict__ out)
{
    __shared__ float Pb[4][16 * 33];

    const int b    = blockIdx.y;
    const int tid  = threadIdx.x;
    const int wave = tid >> 6, lane = tid & 63;
    const int m16  = lane & 15, quad = lane >> 4;
    const int tb   = blockIdx.x * 64 + wave * 16;

    const short* qs = (const short*)qg + (size_t)b * kT * kH;
    const short* ks = (const short*)kg + (size_t)b * kT * kH;
    const short* vs = (const short*)vTg + (size_t)b * kH * kT;

    // K A-frags for this band (k pre-scaled by 384^-0.5 via Wt)
    const bf16x8 ka0 = *(const bf16x8*)(ks + (size_t)(tb + m16) * kH + quad * 8);
    const bf16x8 ka1 = *(const bf16x8*)(ks + (size_t)(tb + m16) * kH + quad * 8 + 32);

    f32x4 O[4];
    float m_[4], l_[4];
#pragma unroll
    for (int i = 0; i < 4; ++i) {
        O[i] = f32x4{0.f, 0.f, 0.f, 0.f};
        m_[i] = -INFINITY; l_[i] = 0.f;
    }
    float* Pw = &Pb[wave][0];

    for (int s0 = 0; s0 < tb + 16; s0 += 32) {
        const short* qb = qs + (size_t)(s0 + m16) * kH + quad * 8;
        bf16x8 q00 = *(const bf16x8*)(qb);
        bf16x8 q01 = *(const bf16x8*)(qb + 32);
        bf16x8 q10 = *(const bf16x8*)(qb + 16 * kH);
        bf16x8 q11 = *(const bf16x8*)(qb + 16 * kH + 32);

        const f32x4 Z = f32x4{0.f, 0.f, 0.f, 0.f};
        f32x4 S0 = __builtin_amdgcn_mfma_f32_16x16x32_bf16(ka0, q00, Z, 0, 0, 0);
        S0       = __builtin_amdgcn_mfma_f32_16x16x32_bf16(ka1, q01, S0, 0, 0, 0);
        f32x4 S1 = __builtin_amdgcn_mfma_f32_16x16x32_bf16(ka0, q10, Z, 0, 0, 0);
        S1       = __builtin_amdgcn_mfma_f32_16x16x32_bf16(ka1, q11, S1, 0, 0, 0);

        if (s0 + 32 > tb) {   // diagonal-crossing chunk: causal mask
#pragma unroll
            for (int r = 0; r < 4; ++r) {
                const int trow = tb + quad * 4 + r;
                if (s0 + m16      > trow) S0[r] = -INFINITY;
                if (s0 + 16 + m16 > trow) S1[r] = -INFINITY;
            }
        }

        float P0[4], P1[4];
#pragma unroll
        for (int r = 0; r < 4; ++r) {
            float rm = fmaxf(S0[r], S1[r]);
            rm = fmaxf(rm, __shfl_xor(rm, 1, 64));
            rm = fmaxf(rm, __shfl_xor(rm, 2, 64));
            rm = fmaxf(rm, __shfl_xor(rm, 4, 64));
            rm = fmaxf(rm, __shfl_xor(rm, 8, 64));
            const float mn = fmaxf(m_[r], rm);
            const float al = __expf(m_[r] - mn);
            m_[r] = mn;
            P0[r] = __expf(S0[r] - mn);
            P1[r] = __expf(S1[r] - mn);
            float rs = P0[r] + P1[r];
            rs += __shfl_xor(rs, 1, 64);
            rs += __shfl_xor(rs, 2, 64);
            rs += __shfl_xor(rs, 4, 64);
            rs += __shfl_xor(rs, 8, 64);
            l_[r] = l_[r] * al + rs;
            O[0][r] *= al; O[1][r] *= al; O[2][r] *= al; O[3][r] *= al;
        }

        // P round-trip: C-layout write, A-layout read (stride 33: 2-way max)
#pragma unroll
        for (int r = 0; r < 4; ++r) {
            Pw[(quad * 4 + r) * 33 + m16]      = P0[r];
            Pw[(quad * 4 + r) * 33 + m16 + 16] = P1[r];
        }
        const float* pr = Pw + m16 * 33 + quad * 8;
        float4 pa = make_float4(pr[0], pr[1], pr[2], pr[3]);
        float4 pc = make_float4(pr[4], pr[5], pr[6], pr[7]);
        bf16x8 pf = cvt8(pa, pc);

#pragma unroll
        for (int ht = 0; ht < 4; ++ht) {
            bf16x8 vf = *(const bf16x8*)(vs + (size_t)(ht * 16 + m16) * kT + s0 + quad * 8);
            O[ht] = __builtin_amdgcn_mfma_f32_16x16x32_bf16(pf, vf, O[ht], 0, 0, 0);
        }
    }

#pragma unroll
    for (int ht = 0; ht < 4; ++ht) {
#pragma unroll
        for (int r = 0; r < 4; ++r) {
            out[(size_t)(b * kT + tb + quad * 4 + r) * kH + ht * 16 + m16] =
                O[ht][r] / l_[r];
        }
    }
}

// ---------------------------------------------------------------------------
extern "C" void kernel_launch(void* const* d_in, const int* in_sizes, int n_in,
                              void* d_out, int out_size, void* d_ws, size_t ws_size,
                              hipStream_t stream) {
    const float* x  = (const float*)d_in[0];
    const float* Wq = (const float*)d_in[1];
    const float* Wk = (const float*)d_in[2];
    const float* Wv = (const float*)d_in[3];
    float* out = (float*)d_out;

    const size_t nqkv = (size_t)kB * kT * kH;           // 2 M elems
    __hip_bfloat16* q  = (__hip_bfloat16*)d_ws;         // 4 MB
    __hip_bfloat16* k  = q + nqkv;                      // 4 MB
    __hip_bfloat16* vT = k + nqkv;                      // 4 MB [b][h][s]
    __hip_bfloat16* Wt = vT + nqkv;                     // 147 KB [n][k]

    prep_kernel<<<(192 * kC) / 256, 256, 0, stream>>>(Wq, Wk, Wv, Wt);
    qkv_kernel<<<(kB * kT) / 64, 256, 0, stream>>>(x, Wt, q, k, vT);
    attn_kernel<<<dim3(kT / 64, kB), 256, 0, stream>>>(q, k, vT, out);
}

// Round 4
// 144.580 us; speedup vs baseline: 4.8448x; 1.0158x over previous
//
#include <hip/hip_runtime.h>
#include <hip/hip_bf16.h>
#include <math.h>

constexpr int kB = 128;
constexpr int kT = 256;
constexpr int kC = 384;
constexpr int kH = 64;

using bf16x8 = __attribute__((ext_vector_type(8))) short;  // 8 bf16 = 4 VGPRs
using f32x4  = __attribute__((ext_vector_type(4))) float;

union BF8 { bf16x8 v; __hip_bfloat162 h[4]; };

__device__ inline bf16x8 cvt8(float4 a, float4 b) {
    BF8 u;
    u.h[0] = __float22bfloat162_rn(float2{a.x, a.y});
    u.h[1] = __float22bfloat162_rn(float2{a.z, a.w});
    u.h[2] = __float22bfloat162_rn(float2{b.x, b.y});
    u.h[3] = __float22bfloat162_rn(float2{b.z, b.w});
    return u.v;
}

// ---------------------------------------------------------------------------
// Kernel 0: Wt[n][k] bf16, n in [0,192) = (w*64+h), k in [0,384).
// Wk rows pre-scaled by 384^-0.5 (k only feeds scores).
// ---------------------------------------------------------------------------
__global__ void prep_kernel(const float* __restrict__ Wq,
                            const float* __restrict__ Wk,
                            const float* __restrict__ Wv,
                            __hip_bfloat16* __restrict__ Wt) {
    int idx = blockIdx.x * 256 + threadIdx.x;     // [0, 192*384)
    int n = idx / kC, c = idx % kC;
    int w = n >> 6, h = n & 63;
    const float* W = (w == 0) ? Wq : (w == 1) ? Wk : Wv;
    float val = W[c * kH + h];
    if (w == 1) val *= 0.051031036307982884f;     // 384^-0.5
    Wt[idx] = __float2bfloat16(val);
}

// ---------------------------------------------------------------------------
// Kernel 1: QKV GEMM, MFMA 16x16x32 bf16. Wave = 16 rows x 192 cols.
// FULL x row prefetched upfront (24 float4 = 24 outstanding HBM loads/wave,
// ~192 KB/CU in flight -> BW-bound, not latency-bound). No LDS, no barriers.
// Grid gives 2 waves/SIMD, so ~210 VGPR is free (halving point is 256).
// ---------------------------------------------------------------------------
__global__ __launch_bounds__(256) void qkv_kernel(
    const float* __restrict__ x, const __hip_bfloat16* __restrict__ Wt,
    __hip_bfloat16* __restrict__ q, __hip_bfloat16* __restrict__ k,
    __hip_bfloat16* __restrict__ vT)
{
    const int tid  = threadIdx.x;
    const int wave = tid >> 6, lane = tid & 63;
    const int m16  = lane & 15, quad = lane >> 4;
    const int rowA = blockIdx.x * 64 + wave * 16 + m16;

    const float* xa = x + (size_t)rowA * kC + quad * 8;
    const short* wt = (const short*)Wt;

    // prefetch entire K=384 strip for this lane: 24 independent loads
    float4 A[24];
#pragma unroll
    for (int c = 0; c < 12; ++c) {
        A[2 * c]     = *(const float4*)(xa + 32 * c);
        A[2 * c + 1] = *(const float4*)(xa + 32 * c + 4);
    }

    f32x4 acc[12];
#pragma unroll
    for (int j = 0; j < 12; ++j) acc[j] = f32x4{0.f, 0.f, 0.f, 0.f};

#pragma unroll
    for (int c = 0; c < 12; ++c) {
        bf16x8 af = cvt8(A[2 * c], A[2 * c + 1]);
#pragma unroll
        for (int j = 0; j < 12; ++j) {
            bf16x8 bf = *(const bf16x8*)(wt + (size_t)(j * 16 + m16) * kC + 32 * c + quad * 8);
            acc[j] = __builtin_amdgcn_mfma_f32_16x16x32_bf16(af, bf, acc[j], 0, 0, 0);
        }
    }

    // epilogue: C-layout col = m16 (within n-tile), row = quad*4 + r
    const int rbase = blockIdx.x * 64 + wave * 16 + quad * 4;
#pragma unroll
    for (int j = 0; j < 12; ++j) {
        const int w = j >> 2;
        const int h = (j & 3) * 16 + m16;
#pragma unroll
        for (int r = 0; r < 4; ++r) {
            const int m = rbase + r;
            __hip_bfloat16 val = __float2bfloat16(acc[j][r]);
            if (w == 0)      q[(size_t)m * kH + h] = val;
            else if (w == 1) k[(size_t)m * kH + h] = val;
            else             vT[((size_t)(m >> 8) * kH + h) * kT + (m & 255)] = val;
        }
    }
}

// ---------------------------------------------------------------------------
// Kernel 2: flash attention, split-KV. Block = 4 waves = 2 bands x 2 s-halves.
// Wave (band, shalf) handles t-band [tb,tb+16), s-chunks s0 = shalf*32 step 64.
// Partials (m,l,O) merged across the two waves of a band via LDS (stride 25,
// conflict-free). Max serial chunks/wave = 4. Grid = 8 x B = 1024 blocks.
// ---------------------------------------------------------------------------
__global__ __launch_bounds__(256) void attn_kernel(
    const __hip_bfloat16* __restrict__ qg, const __hip_bfloat16* __restrict__ kg,
    const __hip_bfloat16* __restrict__ vTg, float* __restrict__ out)
{
    __shared__ float Pb[4][16 * 33];    // per-wave P round-trip
    __shared__ float Mb[2][64 * 25];    // per-band merge: {m[4], l[4], O[16]}/lane

    const int b    = blockIdx.y;
    const int g    = 7 - blockIdx.x;        // heavy bands dispatch first
    const int tid  = threadIdx.x;
    const int wave = tid >> 6, lane = tid & 63;
    const int band = wave >> 1, shalf = wave & 1;
    const int m16  = lane & 15, quad = lane >> 4;
    const int tb   = g * 32 + band * 16;

    const short* qs = (const short*)qg + (size_t)b * kT * kH;
    const short* ks = (const short*)kg + (size_t)b * kT * kH;
    const short* vs = (const short*)vTg + (size_t)b * kH * kT;

    // K A-frags for this band (pre-scaled by 384^-0.5 via Wt)
    const bf16x8 ka0 = *(const bf16x8*)(ks + (size_t)(tb + m16) * kH + quad * 8);
    const bf16x8 ka1 = *(const bf16x8*)(ks + (size_t)(tb + m16) * kH + quad * 8 + 32);

    f32x4 O[4];
    float m_[4], l_[4];
#pragma unroll
    for (int i = 0; i < 4; ++i) {
        O[i] = f32x4{0.f, 0.f, 0.f, 0.f};
        m_[i] = -INFINITY; l_[i] = 0.f;
    }
    float* Pw = &Pb[wave][0];

    for (int s0 = shalf * 32; s0 < tb + 16; s0 += 64) {
        const short* qb = qs + (size_t)(s0 + m16) * kH + quad * 8;
        bf16x8 q00 = *(const bf16x8*)(qb);
        bf16x8 q01 = *(const bf16x8*)(qb + 32);
        bf16x8 q10 = *(const bf16x8*)(qb + 16 * kH);
        bf16x8 q11 = *(const bf16x8*)(qb + 16 * kH + 32);

        const f32x4 Z = f32x4{0.f, 0.f, 0.f, 0.f};
        f32x4 S0 = __builtin_amdgcn_mfma_f32_16x16x32_bf16(ka0, q00, Z, 0, 0, 0);
        S0       = __builtin_amdgcn_mfma_f32_16x16x32_bf16(ka1, q01, S0, 0, 0, 0);
        f32x4 S1 = __builtin_amdgcn_mfma_f32_16x16x32_bf16(ka0, q10, Z, 0, 0, 0);
        S1       = __builtin_amdgcn_mfma_f32_16x16x32_bf16(ka1, q11, S1, 0, 0, 0);

        if (s0 + 32 > tb) {   // diagonal-crossing chunk: causal mask
#pragma unroll
            for (int r = 0; r < 4; ++r) {
                const int trow = tb + quad * 4 + r;
                if (s0 + m16      > trow) S0[r] = -INFINITY;
                if (s0 + 16 + m16 > trow) S1[r] = -INFINITY;
            }
        }

        float P0[4], P1[4];
#pragma unroll
        for (int r = 0; r < 4; ++r) {
            float rm = fmaxf(S0[r], S1[r]);
            rm = fmaxf(rm, __shfl_xor(rm, 1, 64));
            rm = fmaxf(rm, __shfl_xor(rm, 2, 64));
            rm = fmaxf(rm, __shfl_xor(rm, 4, 64));
            rm = fmaxf(rm, __shfl_xor(rm, 8, 64));
            const float mn = fmaxf(m_[r], rm);
            const float al = __expf(m_[r] - mn);
            m_[r] = mn;
            P0[r] = __expf(S0[r] - mn);
            P1[r] = __expf(S1[r] - mn);
            float rs = P0[r] + P1[r];
            rs += __shfl_xor(rs, 1, 64);
            rs += __shfl_xor(rs, 2, 64);
            rs += __shfl_xor(rs, 4, 64);
            rs += __shfl_xor(rs, 8, 64);
            l_[r] = l_[r] * al + rs;
            O[0][r] *= al; O[1][r] *= al; O[2][r] *= al; O[3][r] *= al;
        }

        // P round-trip: C-layout write, A-layout read (stride 33: 2-way max)
#pragma unroll
        for (int r = 0; r < 4; ++r) {
            Pw[(quad * 4 + r) * 33 + m16]      = P0[r];
            Pw[(quad * 4 + r) * 33 + m16 + 16] = P1[r];
        }
        const float* pr = Pw + m16 * 33 + quad * 8;
        float4 pa = make_float4(pr[0], pr[1], pr[2], pr[3]);
        float4 pc = make_float4(pr[4], pr[5], pr[6], pr[7]);
        bf16x8 pf = cvt8(pa, pc);

#pragma unroll
        for (int ht = 0; ht < 4; ++ht) {
            bf16x8 vf = *(const bf16x8*)(vs + (size_t)(ht * 16 + m16) * kT + s0 + quad * 8);
            O[ht] = __builtin_amdgcn_mfma_f32_16x16x32_bf16(pf, vf, O[ht], 0, 0, 0);
        }
    }

    // merge the two s-halves of each band
    if (shalf == 1) {
        float* dst = &Mb[band][lane * 25];
#pragma unroll
        for (int r = 0; r < 4; ++r) { dst[r] = m_[r]; dst[4 + r] = l_[r]; }
#pragma unroll
        for (int ht = 0; ht < 4; ++ht)
#pragma unroll
            for (int r = 0; r < 4; ++r) dst[8 + ht * 4 + r] = O[ht][r];
    }
    __syncthreads();
    if (shalf == 0) {
        const float* src = &Mb[band][lane * 25];
#pragma unroll
        for (int r = 0; r < 4; ++r) {
            const float m1 = src[r], l1 = src[4 + r];
            const float mm = fmaxf(m_[r], m1);
            const float a0 = __expf(m_[r] - mm);
            const float a1 = __expf(m1 - mm);
            const float inv = 1.f / (l_[r] * a0 + l1 * a1);
            const size_t row = (size_t)(b * kT + tb + quad * 4 + r);
#pragma unroll
            for (int ht = 0; ht < 4; ++ht)
                out[row * kH + ht * 16 + m16] =
                    (O[ht][r] * a0 + src[8 + ht * 4 + r] * a1) * inv;
        }
    }
}

// ---------------------------------------------------------------------------
extern "C" void kernel_launch(void* const* d_in, const int* in_sizes, int n_in,
                              void* d_out, int out_size, void* d_ws, size_t ws_size,
                              hipStream_t stream) {
    const float* x  = (const float*)d_in[0];
    const float* Wq = (const float*)d_in[1];
    const float* Wk = (const float*)d_in[2];
    const float* Wv = (const float*)d_in[3];
    float* out = (float*)d_out;

    const size_t nqkv = (size_t)kB * kT * kH;           // 2 M elems
    __hip_bfloat16* q  = (__hip_bfloat16*)d_ws;         // 4 MB
    __hip_bfloat16* k  = q + nqkv;                      // 4 MB
    __hip_bfloat16* vT = k + nqkv;                      // 4 MB [b][h][s]
    __hip_bfloat16* Wt = vT + nqkv;                     // 147 KB [n][k]

    prep_kernel<<<(192 * kC) / 256, 256, 0, stream>>>(Wq, Wk, Wv, Wt);
    qkv_kernel<<<(kB * kT) / 64, 256, 0, stream>>>(x, Wt, q, k, vT);
    attn_kernel<<<dim3(8, kB), 256, 0, stream>>>(q, k, vT, out);
}